// Round 21
// baseline (385.559 us; speedup 1.0000x reference)
//
#include <hip/hip_runtime.h>
#include <hip/hip_bf16.h>

#define USER_NUM 60000
#define ITEM_NUM 40000
#define NODE_NUM 100000
#define DIM 64
#define NNZ_N 1600000
#define BATCH 4096
#define NEG 0.2f
#define BROWS 512                  // rows per bucket
#define NBKT 196                   // ceil(100000/512)
#define PA_EPT 16
#define PA_EPB (256 * PA_EPT)      // 4096 edges per partition block
#define PA_GRID ((NNZ_N + PA_EPB - 1) / PA_EPB)   // 391
#define VAL_DEC 3.0517578125e-07f  // 0.01 / 32768
#define NTILE 6250                 // 100000 / 16 row-tiles
#define SLB ((size_t)NODE_NUM * 16)   // bytes per fp8 dim-slice

typedef unsigned long long u64;
typedef unsigned int u32;
typedef __attribute__((ext_vector_type(8))) short bf16x8;
typedef __attribute__((ext_vector_type(4))) float f32x4;
typedef __attribute__((ext_vector_type(2))) float f32x2;

__device__ __forceinline__ float bf2f(unsigned short u) {
    return __uint_as_float(((u32)u) << 16);
}
__device__ __forceinline__ unsigned short f2bf(float f) {
    u32 x = __float_as_uint(f);
    u32 r = (x + 0x7FFFu + ((x >> 16) & 1u)) >> 16;   // RNE
    return (unsigned short)r;
}
template <bool WORD>
__device__ __forceinline__ int cvt2fp8(u32 u, int old) {
    float lo = __uint_as_float(u << 16);
    float hi = __uint_as_float(u & 0xffff0000u);
    return __builtin_amdgcn_cvt_pk_fp8_f32(lo, hi, old, WORD);
}

// ---- 1. bucket histogram + fused emb->bf16 + fp8 (SLICED layout) conversion ----
__global__ void k_bcount(const int* __restrict__ row, int* __restrict__ bkt_cnt,
                         const float4* __restrict__ csrc, ushort4* __restrict__ dstB,
                         unsigned char* __restrict__ dstF8, int n) {
    __shared__ int h[NBKT];
    int t = threadIdx.x;
    if (t < NBKT) h[t] = 0;
    __syncthreads();
    int base = blockIdx.x * PA_EPB;
#pragma unroll
    for (int j = 0; j < PA_EPT; j++) {
        int idx = base + j * 256 + t;
        if (idx < n) atomicAdd(&h[row[idx] >> 9], 1);
    }
    __syncthreads();
    if (t < NBKT && h[t]) atomicAdd(&bkt_cnt[t], h[t]);
    const int n4 = NODE_NUM * DIM / 4;
    for (int i = blockIdx.x * 256 + t; i < n4; i += PA_GRID * 256) {
        float4 f = csrc[i];
        dstB[i] = make_ushort4(f2bf(f.x), f2bf(f.y), f2bf(f.z), f2bf(f.w));
        int w = __builtin_amdgcn_cvt_pk_fp8_f32(f.x, f.y, 0, false);
        w = __builtin_amdgcn_cvt_pk_fp8_f32(f.z, f.w, w, true);
        int r = i >> 4;            // row (16 float4 per row)
        int q = (i >> 2) & 3;      // slice
        int o = i & 3;             // u32 within slice-row
        *(u32*)&dstF8[(size_t)q * SLB + (size_t)r * 16 + o * 4] = (u32)w;
    }
}

// ---- 2. partition edges into buckets; payload packed u64 (row|col|val15) ----
__launch_bounds__(256)
__global__ void k_passA(const int* __restrict__ row, const int* __restrict__ col,
                        const float* __restrict__ vals, const int* __restrict__ bkt_cnt,
                        int* __restrict__ bcur0, u64* __restrict__ tpk, int n) {
    __shared__ int sb[256];
    __shared__ int gbase[NBKT];
    __shared__ int cur[NBKT];
    __shared__ int gb[NBKT];
    int t = threadIdx.x;
    sb[t] = (t < NBKT) ? bkt_cnt[t] : 0;
    if (t < NBKT) cur[t] = 0;
    __syncthreads();
    for (int d = 1; d < 256; d <<= 1) {
        int x = (t >= d) ? sb[t - d] : 0;
        __syncthreads();
        sb[t] += x;
        __syncthreads();
    }
    if (t < NBKT) gbase[t] = sb[t] - bkt_cnt[t];
    __syncthreads();
    int base = blockIdx.x * PA_EPB;
    u64 pk[PA_EPT];
    int rk[PA_EPT], bk[PA_EPT];
#pragma unroll
    for (int j = 0; j < PA_EPT; j++) {
        int idx = base + j * 256 + t;
        if (idx < n) {
            int r = row[idx];
            int c = col[idx];
            int bits = (int)rintf(vals[idx] * 3276800.0f);
            if (bits > 32767) bits = 32767;
            pk[j] = ((u64)(u32)r << 32) | ((u32)c << 15) | (u32)bits;
            bk[j] = r >> 9;
            rk[j] = atomicAdd(&cur[bk[j]], 1);
        } else bk[j] = -1;
    }
    __syncthreads();
    if (t < NBKT) {
        int cnt = cur[t];
        gb[t] = gbase[t] + (cnt ? atomicAdd(&bcur0[t], cnt) : 0);
    }
    __syncthreads();
#pragma unroll
    for (int j = 0; j < PA_EPT; j++) {
        if (bk[j] >= 0) tpk[gb[bk[j]] + rk[j]] = pk[j];
    }
}

// ---- 3. per-bucket finalize: ptr, packed u32 edges, within-bucket degree sort ----
__launch_bounds__(512)
__global__ void k_passB(const u64* __restrict__ tpk, const int* __restrict__ bkt_cnt,
                        int* __restrict__ ptr, u32* __restrict__ ecv,
                        int* __restrict__ rord) {
    __shared__ int sh[512];
    __shared__ int sb[256];
    __shared__ int h2[64];
    __shared__ int h2c[64];
    int b = blockIdx.x, t = threadIdx.x;
    if (t < 256) sb[t] = (t < NBKT) ? bkt_cnt[t] : 0;
    if (t < 64) { h2[t] = 0; h2c[t] = 0; }
    sh[t] = 0;
    __syncthreads();
    for (int d = 1; d < 256; d <<= 1) {
        int x = 0;
        if (t < 256 && t >= d) x = sb[t - d];
        __syncthreads();
        if (t < 256) sb[t] += x;
        __syncthreads();
    }
    int start = sb[b] - bkt_cnt[b];
    int end = sb[b];
    for (int i = start + t; i < end; i += 512)
        atomicAdd(&sh[(int)(tpk[i] >> 32) & 511], 1);
    __syncthreads();
    int cnt = sh[t];
    int rowg = (b << 9) + t;
    bool valid = (rowg < NODE_NUM);
    int bin = cnt > 63 ? 63 : cnt;
    if (valid) atomicAdd(&h2[bin], 1);
    for (int d = 1; d < 512; d <<= 1) {
        int x = (t >= d) ? sh[t - d] : 0;
        __syncthreads();
        sh[t] += x;
        __syncthreads();
    }
    int excl = sh[t] - cnt;
    if (valid) ptr[rowg] = start + excl;
    if (b == NBKT - 1 && t == 0) ptr[NODE_NUM] = NNZ_N;
    __syncthreads();
    sh[t] = excl;            // running row cursor
    __syncthreads();
    for (int i = start + t; i < end; i += 512) {
        u64 e = tpk[i];
        int r = (int)(e >> 32);
        int pos = start + atomicAdd(&sh[r & 511], 1);
        ecv[pos] = (u32)e;
    }
    __syncthreads();
    if (t < 64) sb[t] = h2[t];
    __syncthreads();
    for (int d = 1; d < 64; d <<= 1) {
        int x = 0;
        if (t < 64 && t >= d) x = sb[t - d];
        __syncthreads();
        if (t < 64) sb[t] += x;
        __syncthreads();
    }
    if (valid) {
        int h2base = sb[bin] - h2[bin];
        int rank = atomicAdd(&h2c[bin], 1);
        rord[(b << 9) + h2base + rank] = rowg;
    }
}

// ---- SpMM v5: dim-sliced. slice = blockIdx&3 -> each XCD's L2 holds ONE
//      1.6MB slice (blockIdx%8 round-robin XCD mapping). 16 rows/wave,
//      4 lanes/row, 4 dims/lane (u32 fp8 read, L2-hit). Heavy tiles first.
__launch_bounds__(256)
__global__ void k_spmm(const int* __restrict__ ptrS, const int* __restrict__ rord,
                       const u32* __restrict__ ecv, const unsigned char* __restrict__ Efs,
                       unsigned short* __restrict__ S) {
    int t = threadIdx.x;
    int w = t >> 6;
    int lane = t & 63;
    int slice = blockIdx.x & 3;
    int tile_rank = (blockIdx.x >> 2) * 4 + w;
    if (tile_rank >= NTILE) return;
    int tile = (NTILE - 1) - tile_rank;          // descending degree
    int rowL = lane >> 2;
    int d4 = lane & 3;
    int r = rord[tile * 16 + rowL];
    int s0 = ptrS[r];
    int e0 = ptrS[r + 1];
    int dm = e0 - s0;
    dm = max(dm, __shfl_xor(dm, 4));
    dm = max(dm, __shfl_xor(dm, 8));
    dm = max(dm, __shfl_xor(dm, 16));
    dm = max(dm, __shfl_xor(dm, 32));
    float a0 = 0.f, a1 = 0.f, a2 = 0.f, a3 = 0.f;
    const unsigned char* T = Efs + (size_t)slice * SLB;
    int srcbase = lane & 60;
    for (int off = 0; off < dm; off += 4) {
        int idx = s0 + off + d4;
        u32 u = (idx < e0) ? __builtin_nontemporal_load(&ecv[idx]) : 0u;
#pragma unroll
        for (int j = 0; j < 4; j++) {
            u32 uu = __shfl(u, srcbase | j);
            float fv = (float)(uu & 0x7fffu);
            u32 g = *(const u32*)&T[(size_t)(uu >> 15) * 16 + d4 * 4];
            f32x2 g01 = __builtin_amdgcn_cvt_pk_f32_fp8(g, false);
            f32x2 g23 = __builtin_amdgcn_cvt_pk_f32_fp8(g, true);
            a0 = fmaf(fv, g01.x, a0);
            a1 = fmaf(fv, g01.y, a1);
            a2 = fmaf(fv, g23.x, a2);
            a3 = fmaf(fv, g23.y, a3);
        }
    }
    u32 o0 = (u32)f2bf(a0 * VAL_DEC) | ((u32)f2bf(a1 * VAL_DEC) << 16);
    u32 o1 = (u32)f2bf(a2 * VAL_DEC) | ((u32)f2bf(a3 * VAL_DEC) << 16);
    *(uint2*)&S[(size_t)r * 64 + slice * 16 + d4 * 4] = make_uint2(o0, o1);
}

// ---- dense: MFMA. Per wave: 16 rows x 64 cols, acc = su@W1 + bi@W2 ----
__launch_bounds__(256)
__global__ void k_dmm(const unsigned short* __restrict__ Ein,
                      const unsigned short* __restrict__ S,
                      const float* __restrict__ W1l, const float* __restrict__ W2l,
                      unsigned short* __restrict__ Eout, unsigned char* __restrict__ Eout8) {
    __shared__ unsigned short cbuf[4][16 * 68];   // per-wave epilogue tile
    int t = threadIdx.x;
    int w = t >> 6;
    int lane = t & 63;
    int r16 = lane & 15;      // A-row / B-col selector
    int g = lane >> 4;        // k-subchunk 0..3 (8 consecutive k each)

    bf16x8 bw[2][2][4];       // [mat][kc][cb] -- all compile-time indices
#pragma unroll
    for (int mat = 0; mat < 2; mat++) {
        const float* W = mat ? W2l : W1l;
#pragma unroll
        for (int kc = 0; kc < 2; kc++) {
#pragma unroll
            for (int cb = 0; cb < 4; cb++) {
                int col = cb * 16 + r16;
                int k0 = kc * 32 + g * 8;
                bf16x8 f;
#pragma unroll
                for (int j = 0; j < 8; j++)
                    f[j] = (short)f2bf(W[(k0 + j) * 64 + col]);
                bw[mat][kc][cb] = f;
            }
        }
    }

    for (int tile = blockIdx.x * 4 + w; tile < NTILE; tile += gridDim.x * 4) {
        int row0 = tile * 16;
        const unsigned short* ep = &Ein[(size_t)(row0 + r16) * 64 + g * 8];
        const unsigned short* sp = &S[(size_t)(row0 + r16) * 64 + g * 8];
        f32x4 ac0 = {0.f, 0.f, 0.f, 0.f};
        f32x4 ac1 = {0.f, 0.f, 0.f, 0.f};
        f32x4 ac2 = {0.f, 0.f, 0.f, 0.f};
        f32x4 ac3 = {0.f, 0.f, 0.f, 0.f};
#pragma unroll
        for (int kc = 0; kc < 2; kc++) {
            bf16x8 ev = *(const bf16x8*)(ep + kc * 32);
            bf16x8 sv = *(const bf16x8*)(sp + kc * 32);
            bf16x8 su, bi;
#pragma unroll
            for (int j = 0; j < 8; j++) {
                float e = bf2f((unsigned short)ev[j]);
                float s = bf2f((unsigned short)sv[j]);
                su[j] = (short)f2bf(e + s);
                bi[j] = (short)f2bf(e * s);
            }
            ac0 = __builtin_amdgcn_mfma_f32_16x16x32_bf16(su, bw[0][kc][0], ac0, 0, 0, 0);
            ac0 = __builtin_amdgcn_mfma_f32_16x16x32_bf16(bi, bw[1][kc][0], ac0, 0, 0, 0);
            ac1 = __builtin_amdgcn_mfma_f32_16x16x32_bf16(su, bw[0][kc][1], ac1, 0, 0, 0);
            ac1 = __builtin_amdgcn_mfma_f32_16x16x32_bf16(bi, bw[1][kc][1], ac1, 0, 0, 0);
            ac2 = __builtin_amdgcn_mfma_f32_16x16x32_bf16(su, bw[0][kc][2], ac2, 0, 0, 0);
            ac2 = __builtin_amdgcn_mfma_f32_16x16x32_bf16(bi, bw[1][kc][2], ac2, 0, 0, 0);
            ac3 = __builtin_amdgcn_mfma_f32_16x16x32_bf16(su, bw[0][kc][3], ac3, 0, 0, 0);
            ac3 = __builtin_amdgcn_mfma_f32_16x16x32_bf16(bi, bw[1][kc][3], ac3, 0, 0, 0);
        }
#pragma unroll
        for (int reg = 0; reg < 4; reg++) {
            int crow = g * 4 + reg;
            float x0 = ac0[reg]; x0 = x0 > 0.f ? x0 : NEG * x0;
            float x1 = ac1[reg]; x1 = x1 > 0.f ? x1 : NEG * x1;
            float x2 = ac2[reg]; x2 = x2 > 0.f ? x2 : NEG * x2;
            float x3 = ac3[reg]; x3 = x3 > 0.f ? x3 : NEG * x3;
            cbuf[w][crow * 68 + 0 * 16 + r16] = f2bf(x0);
            cbuf[w][crow * 68 + 1 * 16 + r16] = f2bf(x1);
            cbuf[w][crow * 68 + 2 * 16 + r16] = f2bf(x2);
            cbuf[w][crow * 68 + 3 * 16 + r16] = f2bf(x3);
        }
        int rrow = lane >> 2;
        int q = lane & 3;
        const uint4* lp = (const uint4*)&cbuf[w][rrow * 68 + q * 16];
        uint4 v0 = lp[0];
        uint4 v1 = lp[1];
        uint4* gp = (uint4*)&Eout[(size_t)(row0 + rrow) * 64 + q * 16];
        gp[0] = v0;
        gp[1] = v1;
        if (Eout8 != nullptr) {
            int w0 = cvt2fp8<false>(v0.x, 0); w0 = cvt2fp8<true>(v0.y, w0);
            int w1 = cvt2fp8<false>(v0.z, 0); w1 = cvt2fp8<true>(v0.w, w1);
            int w2 = cvt2fp8<false>(v1.x, 0); w2 = cvt2fp8<true>(v1.y, w2);
            int w3 = cvt2fp8<false>(v1.z, 0); w3 = cvt2fp8<true>(v1.w, w3);
            // sliced layout: dim-quarter q == slice q
            *(uint4*)&Eout8[(size_t)q * SLB + (size_t)(row0 + rrow) * 16] =
                make_uint4((u32)w0, (u32)w1, (u32)w2, (u32)w3);
        }
    }
}

// ---- final gather: all 4 layer-chunks in one kernel ----
__global__ void k_gatherAll(const float* __restrict__ emb,
                            const unsigned short* __restrict__ E1,
                            const unsigned short* __restrict__ E2,
                            const unsigned short* __restrict__ E3,
                            float* __restrict__ out,
                            const int* __restrict__ uidx, const int* __restrict__ iidx) {
    int g = blockIdx.x * 256 + threadIdx.x;
    int b = g >> 6, d = g & 63;
    if (b >= 2 * BATCH) return;
    int node;
    size_t obase;
    if (b < BATCH) { node = uidx[b]; obase = (size_t)b * 256; }
    else { int bb = b - BATCH; node = USER_NUM + iidx[bb]; obase = (size_t)BATCH * 256 + (size_t)bb * 256; }
    size_t nb = (size_t)node * 64 + d;
    out[obase + d]       = emb[nb];
    out[obase + 64 + d]  = bf2f(E1[nb]);
    out[obase + 128 + d] = bf2f(E2[nb]);
    out[obase + 192 + d] = bf2f(E3[nb]);
}

extern "C" void kernel_launch(void* const* d_in, const int* in_sizes, int n_in,
                              void* d_out, int out_size, void* d_ws, size_t ws_size,
                              hipStream_t stream) {
    const float* emb  = (const float*)d_in[0];
    const float* W1   = (const float*)d_in[1];
    const float* W2   = (const float*)d_in[2];
    const float* vals = (const float*)d_in[3];
    const int*   row  = (const int*)d_in[4];
    const int*   col  = (const int*)d_in[5];
    const int*   uidx = (const int*)d_in[6];
    const int*   iidx = (const int*)d_in[7];
    float* out = (float*)d_out;

    char* p = (char*)d_ws;
    auto alloc = [&](size_t bytes) -> void* {
        void* q = (void*)p;
        p += (bytes + 255) & ~(size_t)255;
        return q;
    };
    int*            ptr      = (int*)alloc((size_t)(NODE_NUM + 1) * 4);
    int*            bcnt_cur = (int*)alloc(512 * 4);   // [0..195]=bkt_cnt, [256..451]=bcur0
    int*            rord     = (int*)alloc((size_t)NODE_NUM * 4);
    u32*            ecv      = (u32*)alloc((size_t)NNZ_N * 4);
    u64*            tpk      = (u64*)alloc((size_t)NNZ_N * 8);
    unsigned short* Sb       = (unsigned short*)alloc((size_t)NODE_NUM * DIM * 2);
    unsigned short* Ebf0     = (unsigned short*)alloc((size_t)NODE_NUM * DIM * 2);
    unsigned short* Eba      = (unsigned short*)alloc((size_t)NODE_NUM * DIM * 2);
    unsigned short* Ebb      = (unsigned short*)alloc((size_t)NODE_NUM * DIM * 2);
    unsigned char*  Ef0      = (unsigned char*)alloc((size_t)NODE_NUM * DIM);
    unsigned char*  Efa      = (unsigned char*)alloc((size_t)NODE_NUM * DIM);
    unsigned char*  Efb      = (unsigned char*)alloc((size_t)NODE_NUM * DIM);
    int* bkt_cnt = bcnt_cur;
    int* bcur0   = bcnt_cur + 256;
    // L2-layer bf16 output aliases tpk (dead after k_passB; sizes fit)
    unsigned short* Ebc = (unsigned short*)tpk;

    // ---- CSR build (4 dispatches), emb->bf16 + sliced-fp8 fused ----
    hipMemsetAsync(bcnt_cur, 0, 512 * 4, stream);
    k_bcount<<<PA_GRID, 256, 0, stream>>>(row, bkt_cnt, (const float4*)emb,
                                          (ushort4*)Ebf0, Ef0, NNZ_N);
    k_passA<<<PA_GRID, 256, 0, stream>>>(row, col, vals, bkt_cnt, bcur0, tpk, NNZ_N);
    k_passB<<<NBKT, 512, 0, stream>>>(tpk, bkt_cnt, ptr, ecv, rord);

    // ---- 3 layers: sliced fp8 spmm -> mfma dense ----
    const int SPMM_GRID = 4 * 1563;   // 6252 blocks: slice=blk&3, 4 tiles/block
    const int DMM_GRID = 391;
    k_spmm<<<SPMM_GRID, 256, 0, stream>>>(ptr, rord, ecv, Ef0, Sb);
    k_dmm<<<DMM_GRID, 256, 0, stream>>>(Ebf0, Sb, W1, W2, Eba, Efa);

    k_spmm<<<SPMM_GRID, 256, 0, stream>>>(ptr, rord, ecv, Efa, Sb);
    k_dmm<<<DMM_GRID, 256, 0, stream>>>(Eba, Sb, W1 + 4096, W2 + 4096, Ebc, Efb);

    k_spmm<<<SPMM_GRID, 256, 0, stream>>>(ptr, rord, ecv, Efb, Sb);
    k_dmm<<<DMM_GRID, 256, 0, stream>>>(Ebc, Sb, W1 + 8192, W2 + 8192, Ebb,
                                        (unsigned char*)nullptr);

    // ---- all output gathers in one kernel ----
    k_gatherAll<<<2048, 256, 0, stream>>>(emb, Eba, Ebc, Ebb, out, uidx, iidx);
}

// Round 22
// 186.197 us; speedup vs baseline: 2.0707x; 2.0707x over previous
//
#include <hip/hip_runtime.h>
#include <hip/hip_bf16.h>

#define USER_NUM 60000
#define ITEM_NUM 40000
#define NODE_NUM 100000
#define DIM 64
#define NNZ_N 1600000
#define BATCH 4096
#define NEG 0.2f
#define BROWS 512                  // rows per bucket
#define NBKT 196                   // ceil(100000/512)
#define PA_EPT 16
#define PA_EPB (256 * PA_EPT)      // 4096 edges per partition block
#define PA_GRID ((NNZ_N + PA_EPB - 1) / PA_EPB)   // 391
#define VAL_DEC 3.0517578125e-07f  // 0.01 / 32768
#define NTILE 6250                 // 100000 / 16 row-tiles

typedef unsigned long long u64;
typedef unsigned int u32;
typedef __attribute__((ext_vector_type(8))) short bf16x8;
typedef __attribute__((ext_vector_type(4))) float f32x4;
typedef __attribute__((ext_vector_type(2))) float f32x2;

__device__ __forceinline__ float bf2f(unsigned short u) {
    return __uint_as_float(((u32)u) << 16);
}
__device__ __forceinline__ unsigned short f2bf(float f) {
    u32 x = __float_as_uint(f);
    u32 r = (x + 0x7FFFu + ((x >> 16) & 1u)) >> 16;   // RNE
    return (unsigned short)r;
}
template <bool WORD>
__device__ __forceinline__ int cvt2fp8(u32 u, int old) {
    float lo = __uint_as_float(u << 16);
    float hi = __uint_as_float(u & 0xffff0000u);
    return __builtin_amdgcn_cvt_pk_fp8_f32(lo, hi, old, WORD);
}

// ---- 1. bucket histogram (LDS-aggregated) + fused emb->bf16/fp8 conversion ----
__global__ void k_bcount(const int* __restrict__ row, int* __restrict__ bkt_cnt,
                         const float4* __restrict__ csrc, ushort4* __restrict__ dstB,
                         u32* __restrict__ dstF, int n) {
    __shared__ int h[NBKT];
    int t = threadIdx.x;
    if (t < NBKT) h[t] = 0;
    __syncthreads();
    int base = blockIdx.x * PA_EPB;
#pragma unroll
    for (int j = 0; j < PA_EPT; j++) {
        int idx = base + j * 256 + t;
        if (idx < n) atomicAdd(&h[row[idx] >> 9], 1);
    }
    __syncthreads();
    if (t < NBKT && h[t]) atomicAdd(&bkt_cnt[t], h[t]);
    const int n4 = NODE_NUM * DIM / 4;
    for (int i = blockIdx.x * 256 + t; i < n4; i += PA_GRID * 256) {
        float4 f = csrc[i];
        dstB[i] = make_ushort4(f2bf(f.x), f2bf(f.y), f2bf(f.z), f2bf(f.w));
        int w = __builtin_amdgcn_cvt_pk_fp8_f32(f.x, f.y, 0, false);
        w = __builtin_amdgcn_cvt_pk_fp8_f32(f.z, f.w, w, true);
        dstF[i] = (u32)w;
    }
}

// ---- 2. partition edges into buckets; payload packed u64 (row|col|val15) ----
__launch_bounds__(256)
__global__ void k_passA(const int* __restrict__ row, const int* __restrict__ col,
                        const float* __restrict__ vals, const int* __restrict__ bkt_cnt,
                        int* __restrict__ bcur0, u64* __restrict__ tpk, int n) {
    __shared__ int sb[256];
    __shared__ int gbase[NBKT];
    __shared__ int cur[NBKT];
    __shared__ int gb[NBKT];
    int t = threadIdx.x;
    sb[t] = (t < NBKT) ? bkt_cnt[t] : 0;
    if (t < NBKT) cur[t] = 0;
    __syncthreads();
    for (int d = 1; d < 256; d <<= 1) {
        int x = (t >= d) ? sb[t - d] : 0;
        __syncthreads();
        sb[t] += x;
        __syncthreads();
    }
    if (t < NBKT) gbase[t] = sb[t] - bkt_cnt[t];
    __syncthreads();
    int base = blockIdx.x * PA_EPB;
    u64 pk[PA_EPT];
    int rk[PA_EPT], bk[PA_EPT];
#pragma unroll
    for (int j = 0; j < PA_EPT; j++) {
        int idx = base + j * 256 + t;
        if (idx < n) {
            int r = row[idx];
            int c = col[idx];
            int bits = (int)rintf(vals[idx] * 3276800.0f);
            if (bits > 32767) bits = 32767;
            pk[j] = ((u64)(u32)r << 32) | ((u32)c << 15) | (u32)bits;
            bk[j] = r >> 9;
            rk[j] = atomicAdd(&cur[bk[j]], 1);
        } else bk[j] = -1;
    }
    __syncthreads();
    if (t < NBKT) {
        int cnt = cur[t];
        gb[t] = gbase[t] + (cnt ? atomicAdd(&bcur0[t], cnt) : 0);
    }
    __syncthreads();
#pragma unroll
    for (int j = 0; j < PA_EPT; j++) {
        if (bk[j] >= 0) tpk[gb[bk[j]] + rk[j]] = pk[j];
    }
}

// ---- 3. per-bucket finalize: ptr, packed u32 edges, within-bucket degree sort ----
__launch_bounds__(512)
__global__ void k_passB(const u64* __restrict__ tpk, const int* __restrict__ bkt_cnt,
                        int* __restrict__ ptr, u32* __restrict__ ecv,
                        int* __restrict__ rord) {
    __shared__ int sh[512];
    __shared__ int sb[256];
    __shared__ int h2[64];
    __shared__ int h2c[64];
    int b = blockIdx.x, t = threadIdx.x;
    if (t < 256) sb[t] = (t < NBKT) ? bkt_cnt[t] : 0;
    if (t < 64) { h2[t] = 0; h2c[t] = 0; }
    sh[t] = 0;
    __syncthreads();
    for (int d = 1; d < 256; d <<= 1) {
        int x = 0;
        if (t < 256 && t >= d) x = sb[t - d];
        __syncthreads();
        if (t < 256) sb[t] += x;
        __syncthreads();
    }
    int start = sb[b] - bkt_cnt[b];
    int end = sb[b];
    for (int i = start + t; i < end; i += 512)
        atomicAdd(&sh[(int)(tpk[i] >> 32) & 511], 1);
    __syncthreads();
    int cnt = sh[t];
    int rowg = (b << 9) + t;
    bool valid = (rowg < NODE_NUM);
    int bin = cnt > 63 ? 63 : cnt;
    if (valid) atomicAdd(&h2[bin], 1);
    for (int d = 1; d < 512; d <<= 1) {
        int x = (t >= d) ? sh[t - d] : 0;
        __syncthreads();
        sh[t] += x;
        __syncthreads();
    }
    int excl = sh[t] - cnt;
    if (valid) ptr[rowg] = start + excl;
    if (b == NBKT - 1 && t == 0) ptr[NODE_NUM] = NNZ_N;
    __syncthreads();
    sh[t] = excl;            // running row cursor
    __syncthreads();
    for (int i = start + t; i < end; i += 512) {
        u64 e = tpk[i];
        int r = (int)(e >> 32);
        int pos = start + atomicAdd(&sh[r & 511], 1);
        ecv[pos] = (u32)e;
    }
    __syncthreads();
    if (t < 64) sb[t] = h2[t];
    __syncthreads();
    for (int d = 1; d < 64; d <<= 1) {
        int x = 0;
        if (t < 64 && t >= d) x = sb[t - d];
        __syncthreads();
        if (t < 64) sb[t] += x;
        __syncthreads();
    }
    if (valid) {
        int h2base = sb[bin] - h2[bin];
        int rank = atomicAdd(&h2c[bin], 1);
        rord[(b << 9) + h2base + rank] = rowg;
    }
}

// ---- fused layer: spmm (16 rows/wave, 4 lanes/row, fp8 gather) -> LDS S ->
//      MFMA dense. No block barrier: per-wave LDS only. Tiles processed in
//      DESCENDING degree order (heavy first) to kill the scheduling tail.
__launch_bounds__(256)
__global__ void k_layer(const int* __restrict__ ptrS, const int* __restrict__ rord,
                        const u32* __restrict__ ecv, const unsigned char* __restrict__ Ef,
                        const unsigned short* __restrict__ Ein,
                        const float* __restrict__ W1l, const float* __restrict__ W2l,
                        unsigned short* __restrict__ Eout, unsigned char* __restrict__ Eout8) {
    __shared__ unsigned short sS[4][16 * 64];     // per-wave S tile (bf16)
    __shared__ unsigned short cbuf[4][16 * 68];   // per-wave epilogue tile
    int t = threadIdx.x;
    int w = t >> 6;
    int lane = t & 63;
    int gwave = blockIdx.x * 4 + w;
    if (gwave >= NTILE) return;     // safe: no cross-wave sync in this kernel
    int tile = (NTILE - 1) - gwave; // heavy (high-degree) tiles first

    // ---- phase A: SpMM for this wave's 16 rows ----
    int rowL = lane >> 2;           // 0..15 row within tile
    int q4 = lane & 3;              // dim quarter: dims q4*16 .. +15
    int arow = rord[tile * 16 + rowL];
    int s0 = ptrS[arow];
    int e0 = ptrS[arow + 1];
    int dm = e0 - s0;
    dm = max(dm, __shfl_xor(dm, 4));
    dm = max(dm, __shfl_xor(dm, 8));
    dm = max(dm, __shfl_xor(dm, 16));
    dm = max(dm, __shfl_xor(dm, 32));
    float acc[16];
#pragma unroll
    for (int q = 0; q < 16; q++) acc[q] = 0.f;
    int srcbase = lane & 60;        // row-group base lane
    for (int off = 0; off < dm; off += 4) {
        int idx = s0 + off + q4;
        u32 u = (idx < e0) ? ecv[idx] : 0u;   // invalid -> c=0, bits=0 (adds 0)
#pragma unroll
        for (int j = 0; j < 4; j++) {
            u32 uu = __shfl(u, srcbase | j);
            float fv = (float)(uu & 0x7fffu);
            uint4 gw = *(const uint4*)&Ef[(size_t)(uu >> 15) * 64 + q4 * 16];
            f32x2 ga = __builtin_amdgcn_cvt_pk_f32_fp8(gw.x, false);
            f32x2 gb = __builtin_amdgcn_cvt_pk_f32_fp8(gw.x, true);
            f32x2 gc = __builtin_amdgcn_cvt_pk_f32_fp8(gw.y, false);
            f32x2 gd = __builtin_amdgcn_cvt_pk_f32_fp8(gw.y, true);
            f32x2 ge = __builtin_amdgcn_cvt_pk_f32_fp8(gw.z, false);
            f32x2 gf = __builtin_amdgcn_cvt_pk_f32_fp8(gw.z, true);
            f32x2 gg = __builtin_amdgcn_cvt_pk_f32_fp8(gw.w, false);
            f32x2 gh = __builtin_amdgcn_cvt_pk_f32_fp8(gw.w, true);
            acc[0]  = fmaf(fv, ga.x, acc[0]);  acc[1]  = fmaf(fv, ga.y, acc[1]);
            acc[2]  = fmaf(fv, gb.x, acc[2]);  acc[3]  = fmaf(fv, gb.y, acc[3]);
            acc[4]  = fmaf(fv, gc.x, acc[4]);  acc[5]  = fmaf(fv, gc.y, acc[5]);
            acc[6]  = fmaf(fv, gd.x, acc[6]);  acc[7]  = fmaf(fv, gd.y, acc[7]);
            acc[8]  = fmaf(fv, ge.x, acc[8]);  acc[9]  = fmaf(fv, ge.y, acc[9]);
            acc[10] = fmaf(fv, gf.x, acc[10]); acc[11] = fmaf(fv, gf.y, acc[11]);
            acc[12] = fmaf(fv, gg.x, acc[12]); acc[13] = fmaf(fv, gg.y, acc[13]);
            acc[14] = fmaf(fv, gh.x, acc[14]); acc[15] = fmaf(fv, gh.y, acc[15]);
        }
    }
    {
        u32 so[8];
#pragma unroll
        for (int q = 0; q < 8; q++) {
            float x0 = acc[2 * q] * VAL_DEC;
            float x1 = acc[2 * q + 1] * VAL_DEC;
            so[q] = (u32)f2bf(x0) | ((u32)f2bf(x1) << 16);
        }
        uint4* sp0 = (uint4*)&sS[w][rowL * 64 + q4 * 16];
        sp0[0] = make_uint4(so[0], so[1], so[2], so[3]);
        sp0[1] = make_uint4(so[4], so[5], so[6], so[7]);
    }

    // ---- phase B: MFMA dense on the same 16 rows (S from LDS) ----
    int r16 = lane & 15;
    int g = lane >> 4;
    bf16x8 bw[2][2][4];
#pragma unroll
    for (int mat = 0; mat < 2; mat++) {
        const float* W = mat ? W2l : W1l;
#pragma unroll
        for (int kc = 0; kc < 2; kc++) {
#pragma unroll
            for (int cb = 0; cb < 4; cb++) {
                int col = cb * 16 + r16;
                int k0 = kc * 32 + g * 8;
                bf16x8 f;
#pragma unroll
                for (int j = 0; j < 8; j++)
                    f[j] = (short)f2bf(W[(k0 + j) * 64 + col]);
                bw[mat][kc][cb] = f;
            }
        }
    }
    int mrow = rord[tile * 16 + r16];
    const unsigned short* ep = &Ein[(size_t)mrow * 64 + g * 8];
    const unsigned short* sp = &sS[w][r16 * 64 + g * 8];
    f32x4 ac0 = {0.f, 0.f, 0.f, 0.f};
    f32x4 ac1 = {0.f, 0.f, 0.f, 0.f};
    f32x4 ac2 = {0.f, 0.f, 0.f, 0.f};
    f32x4 ac3 = {0.f, 0.f, 0.f, 0.f};
#pragma unroll
    for (int kc = 0; kc < 2; kc++) {
        bf16x8 ev = *(const bf16x8*)(ep + kc * 32);
        bf16x8 sv = *(const bf16x8*)(sp + kc * 32);
        bf16x8 su, bi;
#pragma unroll
        for (int j = 0; j < 8; j++) {
            float e = bf2f((unsigned short)ev[j]);
            float s = bf2f((unsigned short)sv[j]);
            su[j] = (short)f2bf(e + s);
            bi[j] = (short)f2bf(e * s);
        }
        ac0 = __builtin_amdgcn_mfma_f32_16x16x32_bf16(su, bw[0][kc][0], ac0, 0, 0, 0);
        ac0 = __builtin_amdgcn_mfma_f32_16x16x32_bf16(bi, bw[1][kc][0], ac0, 0, 0, 0);
        ac1 = __builtin_amdgcn_mfma_f32_16x16x32_bf16(su, bw[0][kc][1], ac1, 0, 0, 0);
        ac1 = __builtin_amdgcn_mfma_f32_16x16x32_bf16(bi, bw[1][kc][1], ac1, 0, 0, 0);
        ac2 = __builtin_amdgcn_mfma_f32_16x16x32_bf16(su, bw[0][kc][2], ac2, 0, 0, 0);
        ac2 = __builtin_amdgcn_mfma_f32_16x16x32_bf16(bi, bw[1][kc][2], ac2, 0, 0, 0);
        ac3 = __builtin_amdgcn_mfma_f32_16x16x32_bf16(su, bw[0][kc][3], ac3, 0, 0, 0);
        ac3 = __builtin_amdgcn_mfma_f32_16x16x32_bf16(bi, bw[1][kc][3], ac3, 0, 0, 0);
    }
#pragma unroll
    for (int reg = 0; reg < 4; reg++) {
        int crow = g * 4 + reg;
        float x0 = ac0[reg]; x0 = x0 > 0.f ? x0 : NEG * x0;
        float x1 = ac1[reg]; x1 = x1 > 0.f ? x1 : NEG * x1;
        float x2 = ac2[reg]; x2 = x2 > 0.f ? x2 : NEG * x2;
        float x3 = ac3[reg]; x3 = x3 > 0.f ? x3 : NEG * x3;
        cbuf[w][crow * 68 + 0 * 16 + r16] = f2bf(x0);
        cbuf[w][crow * 68 + 1 * 16 + r16] = f2bf(x1);
        cbuf[w][crow * 68 + 2 * 16 + r16] = f2bf(x2);
        cbuf[w][crow * 68 + 3 * 16 + r16] = f2bf(x3);
    }
    int rrow = lane >> 2;
    int q = lane & 3;
    int orow = rord[tile * 16 + rrow];
    const uint4* lp = (const uint4*)&cbuf[w][rrow * 68 + q * 16];
    uint4 v0 = lp[0];
    uint4 v1 = lp[1];
    uint4* gp = (uint4*)&Eout[(size_t)orow * 64 + q * 16];
    gp[0] = v0;
    gp[1] = v1;
    if (Eout8 != nullptr) {
        int w0 = cvt2fp8<false>(v0.x, 0); w0 = cvt2fp8<true>(v0.y, w0);
        int w1 = cvt2fp8<false>(v0.z, 0); w1 = cvt2fp8<true>(v0.w, w1);
        int w2 = cvt2fp8<false>(v1.x, 0); w2 = cvt2fp8<true>(v1.y, w2);
        int w3 = cvt2fp8<false>(v1.z, 0); w3 = cvt2fp8<true>(v1.w, w3);
        *(uint4*)&Eout8[(size_t)orow * 64 + q * 16] =
            make_uint4((u32)w0, (u32)w1, (u32)w2, (u32)w3);
    }
}

// ---- final gather: all 4 layer-chunks in one kernel ----
__global__ void k_gatherAll(const float* __restrict__ emb,
                            const unsigned short* __restrict__ E1,
                            const unsigned short* __restrict__ E2,
                            const unsigned short* __restrict__ E3,
                            float* __restrict__ out,
                            const int* __restrict__ uidx, const int* __restrict__ iidx) {
    int g = blockIdx.x * 256 + threadIdx.x;
    int b = g >> 6, d = g & 63;
    if (b >= 2 * BATCH) return;
    int node;
    size_t obase;
    if (b < BATCH) { node = uidx[b]; obase = (size_t)b * 256; }
    else { int bb = b - BATCH; node = USER_NUM + iidx[bb]; obase = (size_t)BATCH * 256 + (size_t)bb * 256; }
    size_t nb = (size_t)node * 64 + d;
    out[obase + d]       = emb[nb];
    out[obase + 64 + d]  = bf2f(E1[nb]);
    out[obase + 128 + d] = bf2f(E2[nb]);
    out[obase + 192 + d] = bf2f(E3[nb]);
}

extern "C" void kernel_launch(void* const* d_in, const int* in_sizes, int n_in,
                              void* d_out, int out_size, void* d_ws, size_t ws_size,
                              hipStream_t stream) {
    const float* emb  = (const float*)d_in[0];
    const float* W1   = (const float*)d_in[1];
    const float* W2   = (const float*)d_in[2];
    const float* vals = (const float*)d_in[3];
    const int*   row  = (const int*)d_in[4];
    const int*   col  = (const int*)d_in[5];
    const int*   uidx = (const int*)d_in[6];
    const int*   iidx = (const int*)d_in[7];
    float* out = (float*)d_out;

    char* p = (char*)d_ws;
    auto alloc = [&](size_t bytes) -> void* {
        void* q = (void*)p;
        p += (bytes + 255) & ~(size_t)255;
        return q;
    };
    int*            ptr      = (int*)alloc((size_t)(NODE_NUM + 1) * 4);
    int*            bcnt_cur = (int*)alloc(512 * 4);   // [0..195]=bkt_cnt, [256..451]=bcur0
    int*            rord     = (int*)alloc((size_t)NODE_NUM * 4);
    u32*            ecv      = (u32*)alloc((size_t)NNZ_N * 4);
    u64*            tpk      = (u64*)alloc((size_t)NNZ_N * 8);
    unsigned short* Ebf0     = (unsigned short*)alloc((size_t)NODE_NUM * DIM * 2);
    unsigned short* Eba      = (unsigned short*)alloc((size_t)NODE_NUM * DIM * 2);
    unsigned short* Ebb      = (unsigned short*)alloc((size_t)NODE_NUM * DIM * 2);
    unsigned char*  Ef0      = (unsigned char*)alloc((size_t)NODE_NUM * DIM);
    unsigned char*  Efa      = (unsigned char*)alloc((size_t)NODE_NUM * DIM);
    unsigned char*  Efb      = (unsigned char*)alloc((size_t)NODE_NUM * DIM);
    int* bkt_cnt = bcnt_cur;
    int* bcur0   = bcnt_cur + 256;
    // L2-layer bf16 output aliases tpk (dead after k_passB; sizes fit)
    unsigned short* Ebc = (unsigned short*)tpk;

    // ---- CSR build (4 dispatches) ----
    hipMemsetAsync(bcnt_cur, 0, 512 * 4, stream);
    k_bcount<<<PA_GRID, 256, 0, stream>>>(row, bkt_cnt, (const float4*)emb,
                                          (ushort4*)Ebf0, (u32*)Ef0, NNZ_N);
    k_passA<<<PA_GRID, 256, 0, stream>>>(row, col, vals, bkt_cnt, bcur0, tpk, NNZ_N);
    k_passB<<<NBKT, 512, 0, stream>>>(tpk, bkt_cnt, ptr, ecv, rord);

    // ---- 3 fused layers: spmm+dense in one kernel each ----
    const int LGRID = (NTILE + 3) / 4;   // 1563 blocks, 1 tile per wave
    k_layer<<<LGRID, 256, 0, stream>>>(ptr, rord, ecv, Ef0, Ebf0, W1, W2, Eba, Efa);
    k_layer<<<LGRID, 256, 0, stream>>>(ptr, rord, ecv, Efa, Eba, W1 + 4096, W2 + 4096, Ebc, Efb);
    k_layer<<<LGRID, 256, 0, stream>>>(ptr, rord, ecv, Efb, Ebc, W1 + 8192, W2 + 8192, Ebb,
                                       (unsigned char*)nullptr);

    // ---- all output gathers in one kernel ----
    k_gatherAll<<<2048, 256, 0, stream>>>(emb, Eba, Ebc, Ebb, out, uidx, iidx);
}